// Round 9
// baseline (1728.125 us; speedup 1.0000x reference)
//
#include <hip/hip_runtime.h>
#include <cstdint>

#define HD 4096
#define FF 11008
#define BB 2
#define LL 2048
#define BL (BB*LL)
#define NN 86          // n-blocks in merged gemm1 grid (2*FF/256)
#define MB1 17         // m-slots in merged gemm1 grid (worst case nL+nV)
#define MB2 17         // m-slots in merged gemm2 grid

using bf16x8  = __attribute__((ext_vector_type(8))) __bf16;
using f32x4   = __attribute__((ext_vector_type(4))) float;
using ushort8 = __attribute__((ext_vector_type(8))) unsigned short;

__device__ __forceinline__ int imin(int a, int b) { return a < b ? a : b; }

__device__ __forceinline__ unsigned short f2bf(float f) {
  union { float f; unsigned u; } v; v.f = f;
  unsigned r = v.u + 0x7fffu + ((v.u >> 16) & 1u);
  return (unsigned short)(r >> 16);
}

__device__ __forceinline__ void gld_lds16(const void* g, void* l) {
  __builtin_amdgcn_global_load_lds(
      (__attribute__((address_space(1))) void*)g,
      (__attribute__((address_space(3))) void*)l, 16, 0, 0);
}
// NT (non-temporal) variant: aux=2 -> CPol.NT on gfx94x/gfx950. Used for
// A-staging (low reuse) so B weight lines stay L2-resident.
__device__ __forceinline__ void gld_lds16_nt(const void* g, void* l) {
  __builtin_amdgcn_global_load_lds(
      (__attribute__((address_space(1))) void*)g,
      (__attribute__((address_space(3))) void*)l, 16, 0, 2);
}

// ---- detect int32 vs int64 storage of token_type_ids ----
__global__ void detect_mode(const int* __restrict__ w, int* __restrict__ flag) {
  int acc = 0;
  for (int i = 1 + 2 * (int)threadIdx.x; i < BL; i += 512) acc |= w[i];
  if (acc != 0) atomicOr(flag, 1);
}

// ---- vision mask + index compaction ----
__global__ void mask_compact(const int* __restrict__ w, const int* __restrict__ flag,
                             int* __restrict__ cnts, int* __restrict__ idxL,
                             int* __restrict__ idxV) {
  int i = blockIdx.x * 256 + threadIdx.x;
  if (i >= BL) return;
  int p = i & (LL - 1);
  bool i32 = (*flag != 0);
  int ti = i32 ? w[i] : w[2 * i];
  bool vis = false;
  if (p < LL - 1) {
    int tn = i32 ? w[i + 1] : w[2 * (i + 1)];
    vis = (ti == 1) && (tn == 1);
  }
  if (vis) idxV[atomicAdd(&cnts[1], 1)] = i;
  else     idxL[atomicAdd(&cnts[0], 1)] = i;
}

// ---- hidden_states fp32 -> bf16 ----
__global__ void convx(const float* __restrict__ x, unsigned short* __restrict__ xb) {
  size_t i = ((size_t)blockIdx.x * 256 + threadIdx.x) * 8;
  float4 a = *(const float4*)(x + i);
  float4 b = *(const float4*)(x + i + 4);
  ushort8 o;
  o[0] = f2bf(a.x); o[1] = f2bf(a.y); o[2] = f2bf(a.z); o[3] = f2bf(a.w);
  o[4] = f2bf(b.x); o[5] = f2bf(b.y); o[6] = f2bf(b.z); o[7] = f2bf(b.w);
  *(ushort8*)(xb + i) = o;
}

// ---- wide weight transpose+convert: in [K][N] fp32 -> out [rmap(N)][K] bf16 ----
// 64(k) x 256(n) tile: 1 KB contiguous row reads, 128 B contiguous row write
// per thread. LDS pad 260 -> 2-way conflicts on the read side (free).
// toff < 0: identity row map; toff 0/16: gate/up 16-row interleave.
__global__ __launch_bounds__(256) void convTW(const float* __restrict__ in,
                                              unsigned short* __restrict__ out,
                                              int K, int N, int toff) {
  __shared__ unsigned short T[64 * 260];
  const int n0 = blockIdx.x * 256, k0 = blockIdx.y * 64;
  const int t = threadIdx.x, w = t >> 6, l = t & 63;
#pragma unroll
  for (int it = 0; it < 16; ++it) {
    int k = it * 4 + w;
    float4 v = *(const float4*)(in + (size_t)(k0 + k) * N + n0 + l * 4);
    unsigned lo = (unsigned)f2bf(v.x) | ((unsigned)f2bf(v.y) << 16);
    unsigned hi = (unsigned)f2bf(v.z) | ((unsigned)f2bf(v.w) << 16);
    *(uint2*)&T[k * 260 + l * 4] = make_uint2(lo, hi);
  }
  __syncthreads();
  const int gn = n0 + t;
  size_t r = (toff < 0) ? (size_t)gn
                        : (size_t)(((gn >> 4) << 5) + toff + (gn & 15));
  unsigned short* op = out + r * K + k0;
#pragma unroll
  for (int c = 0; c < 8; ++c) {
    ushort8 o;
#pragma unroll
    for (int j = 0; j < 8; ++j) o[j] = T[(c * 8 + j) * 260 + t];
    *(ushort8*)(op + c * 8) = o;
  }
}

// ===========================================================================
// Shared 256x256-tile 8-phase pipeline macros (validated round-3/5 ledger):
//   P1 A(kt1)h0   P2 A(kt1)h1   P3 B(kt2)h0   P4 B(kt2)h1 +vmcnt(4)
//   P5 A(kt2)h0   P6 A(kt2)h1   P7 B(kt3)h0   P8 B(kt3)h1 +vmcnt(4)
// A-staging uses NT loads (keep B L2-resident).
// ===========================================================================
#define BAR()  __builtin_amdgcn_s_barrier()
#define VMC(n) asm volatile("s_waitcnt vmcnt(" #n ")" ::: "memory")
#define LGK0() asm volatile("s_waitcnt lgkmcnt(0)" ::: "memory")

#define STG_A(h, kt) { \
  gld_lds16_nt(aptr[h][0] + (size_t)(kt) * 64, &lds[(((kt) & 1) << 14) + ((h) << 13) + w * 512]); \
  gld_lds16_nt(aptr[h][1] + (size_t)(kt) * 64, &lds[(((kt) & 1) << 14) + ((h) << 13) + (w + 8) * 512]); }
#define STG_B(h, kt) { \
  gld_lds16(bptr[h][0] + (size_t)(kt) * 64, &lds[32768 + (((kt) & 1) << 14) + ((h) << 13) + w * 512]); \
  gld_lds16(bptr[h][1] + (size_t)(kt) * 64, &lds[32768 + (((kt) & 1) << 14) + ((h) << 13) + (w + 8) * 512]); }

#define RD_A(s, rh) { _Pragma("unroll") \
  for (int mi = 0; mi < 4; ++mi) { \
    a[mi][0] = *(const bf16x8*)&lds[((s) << 14) + addrA[rh][mi]]; \
    a[mi][1] = *(const bf16x8*)&lds[((s) << 14) + (addrA[rh][mi] ^ 32)]; } }
#define RD_B(s, ch, br) { _Pragma("unroll") \
  for (int ni = 0; ni < 2; ++ni) { \
    br[ni][0] = *(const bf16x8*)&lds[((s) << 14) + addrB[ch][ni]]; \
    br[ni][1] = *(const bf16x8*)&lds[((s) << 14) + (addrB[ch][ni] ^ 32)]; } }

#define MFMA_Q(rh, br, ch) { \
  __builtin_amdgcn_s_setprio(1); \
  _Pragma("unroll") for (int mi = 0; mi < 4; ++mi) \
  _Pragma("unroll") for (int ni = 0; ni < 2; ++ni) { \
    acc[(rh)*4+mi][(ch)*2+ni] = __builtin_amdgcn_mfma_f32_16x16x32_bf16(a[mi][0], br[ni][0], acc[(rh)*4+mi][(ch)*2+ni], 0, 0, 0); \
    acc[(rh)*4+mi][(ch)*2+ni] = __builtin_amdgcn_mfma_f32_16x16x32_bf16(a[mi][1], br[ni][1], acc[(rh)*4+mi][(ch)*2+ni], 0, 0, 0); } \
  __builtin_amdgcn_s_setprio(0); }

// Body: K-loop over KEXT (multiple of 128), using aptr/bptr/addrA/addrB/acc.
#define KLOOP_8PH(KEXT) \
  STG_A(0, 0); STG_A(1, 0); STG_B(0, 0); STG_B(1, 0); \
  STG_B(0, 1); STG_B(1, 1); \
  VMC(4); BAR(); \
  for (int i = 0; i < (KEXT) / 128 - 1; ++i) { \
    const int kt1 = 2 * i + 1, kt2 = 2 * i + 2, kt3 = 2 * i + 3; \
    RD_A(0, 0); RD_B(0, 0, b0); STG_A(0, kt1); BAR(); LGK0(); \
    MFMA_Q(0, b0, 0); BAR(); \
    RD_B(0, 1, b1); STG_A(1, kt1); BAR(); LGK0(); \
    MFMA_Q(0, b1, 1); BAR(); \
    RD_A(0, 1); STG_B(0, kt2); BAR(); LGK0(); \
    MFMA_Q(1, b0, 0); BAR(); \
    STG_B(1, kt2); VMC(4); BAR(); \
    MFMA_Q(1, b1, 1); BAR(); \
    RD_A(1, 0); RD_B(1, 0, b0); STG_A(0, kt2); BAR(); LGK0(); \
    MFMA_Q(0, b0, 0); BAR(); \
    RD_B(1, 1, b1); STG_A(1, kt2); BAR(); LGK0(); \
    MFMA_Q(0, b1, 1); BAR(); \
    RD_A(1, 1); STG_B(0, kt3); BAR(); LGK0(); \
    MFMA_Q(1, b0, 0); BAR(); \
    STG_B(1, kt3); VMC(4); BAR(); \
    MFMA_Q(1, b1, 1); BAR(); \
  } \
  { \
    const int kt1 = (KEXT) / 64 - 1; \
    RD_A(0, 0); RD_B(0, 0, b0); STG_A(0, kt1); BAR(); LGK0(); \
    MFMA_Q(0, b0, 0); BAR(); \
    RD_B(0, 1, b1); STG_A(1, kt1); BAR(); LGK0(); \
    MFMA_Q(0, b1, 1); BAR(); \
    RD_A(0, 1); BAR(); LGK0(); \
    MFMA_Q(1, b0, 0); BAR(); \
    VMC(0); BAR(); \
    MFMA_Q(1, b1, 1); BAR(); \
    RD_A(1, 0); RD_B(1, 0, b0); BAR(); LGK0(); \
    MFMA_Q(0, b0, 0); BAR(); \
    RD_B(1, 1, b1); BAR(); LGK0(); \
    MFMA_Q(0, b1, 1); BAR(); \
    RD_A(1, 1); BAR(); LGK0(); \
    MFMA_Q(1, b0, 0); BAR(); \
    BAR(); \
    MFMA_Q(1, b1, 1); BAR(); \
  }

// ===========================================================================
// GEMM1 merged: both experts, one dispatch. Padded bijective XCD map:
// grid 1464 = 8*183; wgid = xcd*183+pos; bx = wgid/17, mb = wgid%17;
// bx>=86 exits. mb<nL -> lang (idxL,Wgu0) else vis (idxV,Wgu1).
// ===========================================================================
__global__ __launch_bounds__(512, 2) void gemm1m_8ph(
    const unsigned short* __restrict__ Xb,
    const unsigned short* __restrict__ Wgu0, const unsigned short* __restrict__ Wgu1,
    const int* __restrict__ idxL, const int* __restrict__ idxV,
    const int* __restrict__ cnts, unsigned short* __restrict__ H) {
  const int orig = blockIdx.x;
  const int xcd = orig & 7;
  const int pos = orig >> 3;
  const int wgid = xcd * 183 + pos;
  const int bx = wgid / MB1;
  int mb = wgid - bx * MB1;
  if (bx >= NN) return;
  const int cntL = cnts[0], cntV = cnts[1];
  const int nL = (cntL + 255) >> 8;
  const int* idx; const unsigned short* Wgu; int cnt;
  if (mb < nL) { idx = idxL; Wgu = Wgu0; cnt = cntL; }
  else {
    mb -= nL;
    if (mb >= ((cntV + 255) >> 8)) return;
    idx = idxV; Wgu = Wgu1; cnt = cntV;
  }
  const int m0 = mb << 8;

  __shared__ __align__(16) unsigned short lds[65536];

  const int t = threadIdx.x, l = t & 63, w = t >> 6;
  const int wr = w >> 2, wc = w & 3;
  const int srcswz = (((l & 7) ^ (l >> 3)) << 3);

  const unsigned short* aptr[2][2];
  const unsigned short* bptr[2][2];
#pragma unroll
  for (int h = 0; h < 2; ++h)
#pragma unroll
    for (int j = 0; j < 2; ++j) {
      int r = h * 128 + (w + j * 8) * 8 + (l >> 3);
      int tok = idx[imin(m0 + r, cnt - 1)];
      aptr[h][j] = Xb + (size_t)tok * HD + srcswz;
      bptr[h][j] = Wgu + (size_t)(bx * 256 + r) * HD + srcswz;
    }

  const int koff0 = (((l >> 4) ^ (l & 7)) << 3);
  int addrA[2][4], addrB[2][2];
#pragma unroll
  for (int rh = 0; rh < 2; ++rh)
#pragma unroll
    for (int mi = 0; mi < 4; ++mi)
      addrA[rh][mi] = (wr * 128 + rh * 64 + mi * 16 + (l & 15)) * 64 + koff0;
#pragma unroll
  for (int ch = 0; ch < 2; ++ch)
#pragma unroll
    for (int ni = 0; ni < 2; ++ni)
      addrB[ch][ni] = 32768 + (wc * 64 + ch * 32 + ni * 16 + (l & 15)) * 64 + koff0;

  f32x4 acc[8][4] = {};
  bf16x8 a[4][2], b0[2][2], b1[2][2];

  KLOOP_8PH(HD)

#pragma unroll
  for (int mi = 0; mi < 8; ++mi)
#pragma unroll
    for (int j = 0; j < 4; ++j) {
      int grow = m0 + wr * 128 + mi * 16 + ((l >> 4) << 2) + j;
      if (grow < cnt) {
        int token = idx[grow];
#pragma unroll
        for (int pair = 0; pair < 2; ++pair) {
          float g = acc[mi][pair * 2][j];
          float u = acc[mi][pair * 2 + 1][j];
          float h = (g / (1.f + __expf(-g))) * u;
          int f = bx * 128 + wc * 32 + pair * 16 + (l & 15);
          H[(size_t)token * FF + f] = f2bf(h);
        }
      }
    }
}

// ===========================================================================
// GEMM2 merged: out = h @ Wd for BOTH experts in one dispatch.
// Bijective XCD-chunked mapping (272 = 8*34).
// ===========================================================================
__global__ __launch_bounds__(512, 2) void gemm2_8ph(
    const unsigned short* __restrict__ Hh,
    const unsigned short* __restrict__ Wd0, const unsigned short* __restrict__ Wd1,
    const int* __restrict__ idxL, const int* __restrict__ idxV,
    const int* __restrict__ cnts, float* __restrict__ Out) {
  const int orig = blockIdx.x;
  const int xcd = orig & 7;
  const int pos = orig >> 3;
  const int wgid = xcd * ((HD / 256) * MB2 / 8) + pos;   // 34 per XCD
  const int bx = wgid / MB2;
  int mb = wgid - bx * MB2;
  const int cntL = cnts[0], cntV = cnts[1];
  const int nL = (cntL + 255) >> 8;
  const int* idx; const unsigned short* Wd; int cnt;
  if (mb < nL) { idx = idxL; Wd = Wd0; cnt = cntL; }
  else {
    mb -= nL;
    if (mb >= ((cntV + 255) >> 8)) return;
    idx = idxV; Wd = Wd1; cnt = cntV;
  }
  const int m0 = mb << 8;

  __shared__ __align__(16) unsigned short lds[65536];

  const int t = threadIdx.x, l = t & 63, w = t >> 6;
  const int wr = w >> 2, wc = w & 3;
  const int srcswz = (((l & 7) ^ (l >> 3)) << 3);

  const unsigned short* aptr[2][2];
  const unsigned short* bptr[2][2];
#pragma unroll
  for (int h = 0; h < 2; ++h)
#pragma unroll
    for (int j = 0; j < 2; ++j) {
      int r = h * 128 + (w + j * 8) * 8 + (l >> 3);
      int tok = idx[imin(m0 + r, cnt - 1)];
      aptr[h][j] = Hh + (size_t)tok * FF + srcswz;
      bptr[h][j] = Wd + (size_t)(bx * 256 + r) * FF + srcswz;
    }

  const int koff0 = (((l >> 4) ^ (l & 7)) << 3);
  int addrA[2][4], addrB[2][2];
#pragma unroll
  for (int rh = 0; rh < 2; ++rh)
#pragma unroll
    for (int mi = 0; mi < 4; ++mi)
      addrA[rh][mi] = (wr * 128 + rh * 64 + mi * 16 + (l & 15)) * 64 + koff0;
#pragma unroll
  for (int ch = 0; ch < 2; ++ch)
#pragma unroll
    for (int ni = 0; ni < 2; ++ni)
      addrB[ch][ni] = 32768 + (wc * 64 + ch * 32 + ni * 16 + (l & 15)) * 64 + koff0;

  f32x4 acc[8][4] = {};
  bf16x8 a[4][2], b0[2][2], b1[2][2];

  KLOOP_8PH(FF)

#pragma unroll
  for (int mi = 0; mi < 8; ++mi)
#pragma unroll
    for (int j = 0; j < 4; ++j) {
      int grow = m0 + wr * 128 + mi * 16 + ((l >> 4) << 2) + j;
      if (grow < cnt) {
        int token = idx[grow];
        size_t base = (size_t)token * HD + bx * 256 + wc * 64 + (l & 15);
#pragma unroll
        for (int nf = 0; nf < 4; ++nf)
          Out[base + nf * 16] = acc[mi][nf][j];
      }
    }
}

extern "C" void kernel_launch(void* const* d_in, const int* in_sizes, int n_in,
                              void* d_out, int out_size, void* d_ws, size_t ws_size,
                              hipStream_t stream) {
  const float* hs = (const float*)d_in[0];
  const int*   tt = (const int*)d_in[1];
  const float* lg = (const float*)d_in[2];
  const float* lu = (const float*)d_in[3];
  const float* ld = (const float*)d_in[4];
  const float* vg = (const float*)d_in[5];
  const float* vu = (const float*)d_in[6];
  const float* vd = (const float*)d_in[7];
  float* out = (float*)d_out;
  char* ws = (char*)d_ws;

  int* cnts = (int*)ws;
  int* flag = (int*)(ws + 8);
  int* idxL = (int*)(ws + 1024);
  int* idxV = (int*)(ws + 1024 + BL * 4);
  unsigned short* Xb   = (unsigned short*)(ws + 65536);
  unsigned short* Hb   = Xb + (size_t)BL * HD;
  unsigned short* Wgu0 = Hb + (size_t)BL * FF;          // 180.4 MB
  unsigned short* Wgu1 = Wgu0 + (size_t)2 * HD * FF;    // 180.4 MB
  unsigned short* Wd0  = Wgu0;                          // reused after gemm1
  unsigned short* Wd1  = Wgu0 + (size_t)HD * FF;

  hipMemsetAsync(ws, 0, 64, stream);
  detect_mode<<<1, 256, 0, stream>>>(tt, flag);
  mask_compact<<<BL / 256, 256, 0, stream>>>(tt, flag, cnts, idxL, idxV);
  convx<<<(BL * HD / 8) / 256, 256, 0, stream>>>(hs, Xb);

  // both experts' gate/up interleaved -> one merged gemm1 dispatch
  convTW<<<dim3(FF / 256, HD / 64), 256, 0, stream>>>(lg, Wgu0, HD, FF, 0);
  convTW<<<dim3(FF / 256, HD / 64), 256, 0, stream>>>(lu, Wgu0, HD, FF, 16);
  convTW<<<dim3(FF / 256, HD / 64), 256, 0, stream>>>(vg, Wgu1, HD, FF, 0);
  convTW<<<dim3(FF / 256, HD / 64), 256, 0, stream>>>(vu, Wgu1, HD, FF, 16);
  gemm1m_8ph<<<dim3(8 * 183), 512, 0, stream>>>(Xb, Wgu0, Wgu1, idxL, idxV, cnts, Hb);

  // down projections: both experts' Wd into the freed Wgu region, one merged GEMM
  convTW<<<dim3(HD / 256, FF / 64), 256, 0, stream>>>(ld, Wd0, FF, HD, -1);
  convTW<<<dim3(HD / 256, FF / 64), 256, 0, stream>>>(vd, Wd1, FF, HD, -1);
  gemm2_8ph<<<dim3((HD / 256) * MB2), 512, 0, stream>>>(Hb, Wd0, Wd1, idxL, idxV, cnts, out);
}

// Round 10
// 1579.655 us; speedup vs baseline: 1.0940x; 1.0940x over previous
//
#include <hip/hip_runtime.h>
#include <cstdint>

#define HD 4096
#define FF 11008
#define BB 2
#define LL 2048
#define BL (BB*LL)
#define NN 86          // n-blocks in merged gemm1 grid (2*FF/256)
#define MB1 17         // m-slots in merged gemm1 grid (worst case nL+nV)
#define MB2 17         // m-slots in merged gemm2 grid

using bf16x8  = __attribute__((ext_vector_type(8))) __bf16;
using f32x4   = __attribute__((ext_vector_type(4))) float;
using ushort8 = __attribute__((ext_vector_type(8))) unsigned short;

__device__ __forceinline__ int imin(int a, int b) { return a < b ? a : b; }

__device__ __forceinline__ unsigned short f2bf(float f) {
  union { float f; unsigned u; } v; v.f = f;
  unsigned r = v.u + 0x7fffu + ((v.u >> 16) & 1u);
  return (unsigned short)(r >> 16);
}

__device__ __forceinline__ void gld_lds16(const void* g, void* l) {
  __builtin_amdgcn_global_load_lds(
      (__attribute__((address_space(1))) void*)g,
      (__attribute__((address_space(3))) void*)l, 16, 0, 0);
}

// ---- detect int32 vs int64 storage of token_type_ids ----
__global__ void detect_mode(const int* __restrict__ w, int* __restrict__ flag) {
  int acc = 0;
  for (int i = 1 + 2 * (int)threadIdx.x; i < BL; i += 512) acc |= w[i];
  if (acc != 0) atomicOr(flag, 1);
}

// ---- vision mask + index compaction ----
__global__ void mask_compact(const int* __restrict__ w, const int* __restrict__ flag,
                             int* __restrict__ cnts, int* __restrict__ idxL,
                             int* __restrict__ idxV) {
  int i = blockIdx.x * 256 + threadIdx.x;
  if (i >= BL) return;
  int p = i & (LL - 1);
  bool i32 = (*flag != 0);
  int ti = i32 ? w[i] : w[2 * i];
  bool vis = false;
  if (p < LL - 1) {
    int tn = i32 ? w[i + 1] : w[2 * (i + 1)];
    vis = (ti == 1) && (tn == 1);
  }
  if (vis) idxV[atomicAdd(&cnts[1], 1)] = i;
  else     idxL[atomicAdd(&cnts[0], 1)] = i;
}

// ---- hidden_states fp32 -> bf16 ----
__global__ void convx(const float* __restrict__ x, unsigned short* __restrict__ xb) {
  size_t i = ((size_t)blockIdx.x * 256 + threadIdx.x) * 8;
  float4 a = *(const float4*)(x + i);
  float4 b = *(const float4*)(x + i + 4);
  ushort8 o;
  o[0] = f2bf(a.x); o[1] = f2bf(a.y); o[2] = f2bf(a.z); o[3] = f2bf(a.w);
  o[4] = f2bf(b.x); o[5] = f2bf(b.y); o[6] = f2bf(b.z); o[7] = f2bf(b.w);
  *(ushort8*)(xb + i) = o;
}

// ---- wide weight transpose+convert: in [K][N] fp32 -> out [rmap(N)][K] bf16 ----
// 64(k) x 256(n) tile: 1 KB contiguous row reads, 128 B contiguous row write
// per thread. LDS pad 260 -> 2-way conflicts on the read side (free).
// toff < 0: identity row map; toff 0/16: gate/up 16-row interleave.
__global__ __launch_bounds__(256) void convTW(const float* __restrict__ in,
                                              unsigned short* __restrict__ out,
                                              int K, int N, int toff) {
  __shared__ unsigned short T[64 * 260];
  const int n0 = blockIdx.x * 256, k0 = blockIdx.y * 64;
  const int t = threadIdx.x, w = t >> 6, l = t & 63;
#pragma unroll
  for (int it = 0; it < 16; ++it) {
    int k = it * 4 + w;
    float4 v = *(const float4*)(in + (size_t)(k0 + k) * N + n0 + l * 4);
    unsigned lo = (unsigned)f2bf(v.x) | ((unsigned)f2bf(v.y) << 16);
    unsigned hi = (unsigned)f2bf(v.z) | ((unsigned)f2bf(v.w) << 16);
    *(uint2*)&T[k * 260 + l * 4] = make_uint2(lo, hi);
  }
  __syncthreads();
  const int gn = n0 + t;
  size_t r = (toff < 0) ? (size_t)gn
                        : (size_t)(((gn >> 4) << 5) + toff + (gn & 15));
  unsigned short* op = out + r * K + k0;
#pragma unroll
  for (int c = 0; c < 8; ++c) {
    ushort8 o;
#pragma unroll
    for (int j = 0; j < 8; ++j) o[j] = T[(c * 8 + j) * 260 + t];
    *(ushort8*)(op + c * 8) = o;
  }
}

// ===========================================================================
// Shared 256x256-tile 8-phase pipeline macros (validated round-3/5 ledger):
//   P1 A(kt1)h0   P2 A(kt1)h1   P3 B(kt2)h0   P4 B(kt2)h1 +vmcnt(4)
//   P5 A(kt2)h0   P6 A(kt2)h1   P7 B(kt3)h0   P8 B(kt3)h1 +vmcnt(4)
// ===========================================================================
#define BAR()  __builtin_amdgcn_s_barrier()
#define VMC(n) asm volatile("s_waitcnt vmcnt(" #n ")" ::: "memory")
#define LGK0() asm volatile("s_waitcnt lgkmcnt(0)" ::: "memory")

#define STG_A(h, kt) { \
  gld_lds16(aptr[h][0] + (size_t)(kt) * 64, &lds[(((kt) & 1) << 14) + ((h) << 13) + w * 512]); \
  gld_lds16(aptr[h][1] + (size_t)(kt) * 64, &lds[(((kt) & 1) << 14) + ((h) << 13) + (w + 8) * 512]); }
#define STG_B(h, kt) { \
  gld_lds16(bptr[h][0] + (size_t)(kt) * 64, &lds[32768 + (((kt) & 1) << 14) + ((h) << 13) + w * 512]); \
  gld_lds16(bptr[h][1] + (size_t)(kt) * 64, &lds[32768 + (((kt) & 1) << 14) + ((h) << 13) + (w + 8) * 512]); }

#define RD_A(s, rh) { _Pragma("unroll") \
  for (int mi = 0; mi < 4; ++mi) { \
    a[mi][0] = *(const bf16x8*)&lds[((s) << 14) + addrA[rh][mi]]; \
    a[mi][1] = *(const bf16x8*)&lds[((s) << 14) + (addrA[rh][mi] ^ 32)]; } }
#define RD_B(s, ch, br) { _Pragma("unroll") \
  for (int ni = 0; ni < 2; ++ni) { \
    br[ni][0] = *(const bf16x8*)&lds[((s) << 14) + addrB[ch][ni]]; \
    br[ni][1] = *(const bf16x8*)&lds[((s) << 14) + (addrB[ch][ni] ^ 32)]; } }

#define MFMA_Q(rh, br, ch) { \
  __builtin_amdgcn_s_setprio(1); \
  _Pragma("unroll") for (int mi = 0; mi < 4; ++mi) \
  _Pragma("unroll") for (int ni = 0; ni < 2; ++ni) { \
    acc[(rh)*4+mi][(ch)*2+ni] = __builtin_amdgcn_mfma_f32_16x16x32_bf16(a[mi][0], br[ni][0], acc[(rh)*4+mi][(ch)*2+ni], 0, 0, 0); \
    acc[(rh)*4+mi][(ch)*2+ni] = __builtin_amdgcn_mfma_f32_16x16x32_bf16(a[mi][1], br[ni][1], acc[(rh)*4+mi][(ch)*2+ni], 0, 0, 0); } \
  __builtin_amdgcn_s_setprio(0); }

// Body: K-loop over KEXT (multiple of 128), using aptr/bptr/addrA/addrB/acc.
#define KLOOP_8PH(KEXT) \
  STG_A(0, 0); STG_A(1, 0); STG_B(0, 0); STG_B(1, 0); \
  STG_B(0, 1); STG_B(1, 1); \
  VMC(4); BAR(); \
  for (int i = 0; i < (KEXT) / 128 - 1; ++i) { \
    const int kt1 = 2 * i + 1, kt2 = 2 * i + 2, kt3 = 2 * i + 3; \
    RD_A(0, 0); RD_B(0, 0, b0); STG_A(0, kt1); BAR(); LGK0(); \
    MFMA_Q(0, b0, 0); BAR(); \
    RD_B(0, 1, b1); STG_A(1, kt1); BAR(); LGK0(); \
    MFMA_Q(0, b1, 1); BAR(); \
    RD_A(0, 1); STG_B(0, kt2); BAR(); LGK0(); \
    MFMA_Q(1, b0, 0); BAR(); \
    STG_B(1, kt2); VMC(4); BAR(); \
    MFMA_Q(1, b1, 1); BAR(); \
    RD_A(1, 0); RD_B(1, 0, b0); STG_A(0, kt2); BAR(); LGK0(); \
    MFMA_Q(0, b0, 0); BAR(); \
    RD_B(1, 1, b1); STG_A(1, kt2); BAR(); LGK0(); \
    MFMA_Q(0, b1, 1); BAR(); \
    RD_A(1, 1); STG_B(0, kt3); BAR(); LGK0(); \
    MFMA_Q(1, b0, 0); BAR(); \
    STG_B(1, kt3); VMC(4); BAR(); \
    MFMA_Q(1, b1, 1); BAR(); \
  } \
  { \
    const int kt1 = (KEXT) / 64 - 1; \
    RD_A(0, 0); RD_B(0, 0, b0); STG_A(0, kt1); BAR(); LGK0(); \
    MFMA_Q(0, b0, 0); BAR(); \
    RD_B(0, 1, b1); STG_A(1, kt1); BAR(); LGK0(); \
    MFMA_Q(0, b1, 1); BAR(); \
    RD_A(0, 1); BAR(); LGK0(); \
    MFMA_Q(1, b0, 0); BAR(); \
    VMC(0); BAR(); \
    MFMA_Q(1, b1, 1); BAR(); \
    RD_A(1, 0); RD_B(1, 0, b0); BAR(); LGK0(); \
    MFMA_Q(0, b0, 0); BAR(); \
    RD_B(1, 1, b1); BAR(); LGK0(); \
    MFMA_Q(0, b1, 1); BAR(); \
    RD_A(1, 1); BAR(); LGK0(); \
    MFMA_Q(1, b0, 0); BAR(); \
    BAR(); \
    MFMA_Q(1, b1, 1); BAR(); \
  }

// ===========================================================================
// GEMM1 merged: both experts, one dispatch. Padded bijective XCD map:
// grid 1464 = 8*183; wgid = xcd*183+pos; bx = wgid/17, mb = wgid%17;
// bx>=86 exits. mb<nL -> lang (idxL,Wgu0) else vis (idxV,Wgu1).
// ===========================================================================
__global__ __launch_bounds__(512, 2) void gemm1m_8ph(
    const unsigned short* __restrict__ Xb,
    const unsigned short* __restrict__ Wgu0, const unsigned short* __restrict__ Wgu1,
    const int* __restrict__ idxL, const int* __restrict__ idxV,
    const int* __restrict__ cnts, unsigned short* __restrict__ H) {
  const int orig = blockIdx.x;
  const int xcd = orig & 7;
  const int pos = orig >> 3;
  const int wgid = xcd * 183 + pos;
  const int bx = wgid / MB1;
  int mb = wgid - bx * MB1;
  if (bx >= NN) return;
  const int cntL = cnts[0], cntV = cnts[1];
  const int nL = (cntL + 255) >> 8;
  const int* idx; const unsigned short* Wgu; int cnt;
  if (mb < nL) { idx = idxL; Wgu = Wgu0; cnt = cntL; }
  else {
    mb -= nL;
    if (mb >= ((cntV + 255) >> 8)) return;
    idx = idxV; Wgu = Wgu1; cnt = cntV;
  }
  const int m0 = mb << 8;

  __shared__ __align__(16) unsigned short lds[65536];

  const int t = threadIdx.x, l = t & 63, w = t >> 6;
  const int wr = w >> 2, wc = w & 3;
  const int srcswz = (((l & 7) ^ (l >> 3)) << 3);

  const unsigned short* aptr[2][2];
  const unsigned short* bptr[2][2];
#pragma unroll
  for (int h = 0; h < 2; ++h)
#pragma unroll
    for (int j = 0; j < 2; ++j) {
      int r = h * 128 + (w + j * 8) * 8 + (l >> 3);
      int tok = idx[imin(m0 + r, cnt - 1)];
      aptr[h][j] = Xb + (size_t)tok * HD + srcswz;
      bptr[h][j] = Wgu + (size_t)(bx * 256 + r) * HD + srcswz;
    }

  const int koff0 = (((l >> 4) ^ (l & 7)) << 3);
  int addrA[2][4], addrB[2][2];
#pragma unroll
  for (int rh = 0; rh < 2; ++rh)
#pragma unroll
    for (int mi = 0; mi < 4; ++mi)
      addrA[rh][mi] = (wr * 128 + rh * 64 + mi * 16 + (l & 15)) * 64 + koff0;
#pragma unroll
  for (int ch = 0; ch < 2; ++ch)
#pragma unroll
    for (int ni = 0; ni < 2; ++ni)
      addrB[ch][ni] = 32768 + (wc * 64 + ch * 32 + ni * 16 + (l & 15)) * 64 + koff0;

  f32x4 acc[8][4] = {};
  bf16x8 a[4][2], b0[2][2], b1[2][2];

  KLOOP_8PH(HD)

#pragma unroll
  for (int mi = 0; mi < 8; ++mi)
#pragma unroll
    for (int j = 0; j < 4; ++j) {
      int grow = m0 + wr * 128 + mi * 16 + ((l >> 4) << 2) + j;
      if (grow < cnt) {
        int token = idx[grow];
#pragma unroll
        for (int pair = 0; pair < 2; ++pair) {
          float g = acc[mi][pair * 2][j];
          float u = acc[mi][pair * 2 + 1][j];
          float h = (g / (1.f + __expf(-g))) * u;
          int f = bx * 128 + wc * 32 + pair * 16 + (l & 15);
          H[(size_t)token * FF + f] = f2bf(h);
        }
      }
    }
}

// ===========================================================================
// GEMM2 merged: out = h @ Wd for BOTH experts in one dispatch.
// Bijective XCD-chunked mapping (272 = 8*34).
// ===========================================================================
__global__ __launch_bounds__(512, 2) void gemm2_8ph(
    const unsigned short* __restrict__ Hh,
    const unsigned short* __restrict__ Wd0, const unsigned short* __restrict__ Wd1,
    const int* __restrict__ idxL, const int* __restrict__ idxV,
    const int* __restrict__ cnts, float* __restrict__ Out) {
  const int orig = blockIdx.x;
  const int xcd = orig & 7;
  const int pos = orig >> 3;
  const int wgid = xcd * ((HD / 256) * MB2 / 8) + pos;   // 34 per XCD
  const int bx = wgid / MB2;
  int mb = wgid - bx * MB2;
  const int cntL = cnts[0], cntV = cnts[1];
  const int nL = (cntL + 255) >> 8;
  const int* idx; const unsigned short* Wd; int cnt;
  if (mb < nL) { idx = idxL; Wd = Wd0; cnt = cntL; }
  else {
    mb -= nL;
    if (mb >= ((cntV + 255) >> 8)) return;
    idx = idxV; Wd = Wd1; cnt = cntV;
  }
  const int m0 = mb << 8;

  __shared__ __align__(16) unsigned short lds[65536];

  const int t = threadIdx.x, l = t & 63, w = t >> 6;
  const int wr = w >> 2, wc = w & 3;
  const int srcswz = (((l & 7) ^ (l >> 3)) << 3);

  const unsigned short* aptr[2][2];
  const unsigned short* bptr[2][2];
#pragma unroll
  for (int h = 0; h < 2; ++h)
#pragma unroll
    for (int j = 0; j < 2; ++j) {
      int r = h * 128 + (w + j * 8) * 8 + (l >> 3);
      int tok = idx[imin(m0 + r, cnt - 1)];
      aptr[h][j] = Hh + (size_t)tok * FF + srcswz;
      bptr[h][j] = Wd + (size_t)(bx * 256 + r) * FF + srcswz;
    }

  const int koff0 = (((l >> 4) ^ (l & 7)) << 3);
  int addrA[2][4], addrB[2][2];
#pragma unroll
  for (int rh = 0; rh < 2; ++rh)
#pragma unroll
    for (int mi = 0; mi < 4; ++mi)
      addrA[rh][mi] = (wr * 128 + rh * 64 + mi * 16 + (l & 15)) * 64 + koff0;
#pragma unroll
  for (int ch = 0; ch < 2; ++ch)
#pragma unroll
    for (int ni = 0; ni < 2; ++ni)
      addrB[ch][ni] = 32768 + (wc * 64 + ch * 32 + ni * 16 + (l & 15)) * 64 + koff0;

  f32x4 acc[8][4] = {};
  bf16x8 a[4][2], b0[2][2], b1[2][2];

  KLOOP_8PH(FF)

#pragma unroll
  for (int mi = 0; mi < 8; ++mi)
#pragma unroll
    for (int j = 0; j < 4; ++j) {
      int grow = m0 + wr * 128 + mi * 16 + ((l >> 4) << 2) + j;
      if (grow < cnt) {
        int token = idx[grow];
        size_t base = (size_t)token * HD + bx * 256 + wc * 64 + (l & 15);
#pragma unroll
        for (int nf = 0; nf < 4; ++nf)
          Out[base + nf * 16] = acc[mi][nf][j];
      }
    }
}

extern "C" void kernel_launch(void* const* d_in, const int* in_sizes, int n_in,
                              void* d_out, int out_size, void* d_ws, size_t ws_size,
                              hipStream_t stream) {
  const float* hs = (const float*)d_in[0];
  const int*   tt = (const int*)d_in[1];
  const float* lg = (const float*)d_in[2];
  const float* lu = (const float*)d_in[3];
  const float* ld = (const float*)d_in[4];
  const float* vg = (const float*)d_in[5];
  const float* vu = (const float*)d_in[6];
  const float* vd = (const float*)d_in[7];
  float* out = (float*)d_out;
  char* ws = (char*)d_ws;

  int* cnts = (int*)ws;
  int* flag = (int*)(ws + 8);
  int* idxL = (int*)(ws + 1024);
  int* idxV = (int*)(ws + 1024 + BL * 4);
  unsigned short* Xb   = (unsigned short*)(ws + 65536);
  unsigned short* Hb   = Xb + (size_t)BL * HD;
  unsigned short* Wgu0 = Hb + (size_t)BL * FF;          // 180.4 MB
  unsigned short* Wgu1 = Wgu0 + (size_t)2 * HD * FF;    // 180.4 MB
  unsigned short* Wd0  = Wgu0;                          // reused after gemm1
  unsigned short* Wd1  = Wgu0 + (size_t)HD * FF;

  hipMemsetAsync(ws, 0, 64, stream);
  detect_mode<<<1, 256, 0, stream>>>(tt, flag);
  mask_compact<<<BL / 256, 256, 0, stream>>>(tt, flag, cnts, idxL, idxV);
  convx<<<(BL * HD / 8) / 256, 256, 0, stream>>>(hs, Xb);

  // both experts' gate/up interleaved -> one merged gemm1 dispatch
  convTW<<<dim3(FF / 256, HD / 64), 256, 0, stream>>>(lg, Wgu0, HD, FF, 0);
  convTW<<<dim3(FF / 256, HD / 64), 256, 0, stream>>>(lu, Wgu0, HD, FF, 16);
  convTW<<<dim3(FF / 256, HD / 64), 256, 0, stream>>>(vg, Wgu1, HD, FF, 0);
  convTW<<<dim3(FF / 256, HD / 64), 256, 0, stream>>>(vu, Wgu1, HD, FF, 16);
  gemm1m_8ph<<<dim3(8 * 183), 512, 0, stream>>>(Xb, Wgu0, Wgu1, idxL, idxV, cnts, Hb);

  // down projections: both experts' Wd into the freed Wgu region, one merged GEMM
  convTW<<<dim3(HD / 256, FF / 64), 256, 0, stream>>>(ld, Wd0, FF, HD, -1);
  convTW<<<dim3(HD / 256, FF / 64), 256, 0, stream>>>(vd, Wd1, FF, HD, -1);
  gemm2_8ph<<<dim3((HD / 256) * MB2), 512, 0, stream>>>(Hb, Wd0, Wd1, idxL, idxV, cnts, out);
}

// Round 11
// 1447.026 us; speedup vs baseline: 1.1943x; 1.0917x over previous
//
#include <hip/hip_runtime.h>
#include <cstdint>

#define HD 4096
#define FF 11008
#define BB 2
#define LL 2048
#define BL (BB*LL)
#define NN 86          // n-blocks in merged gemm1 grid (2*FF/256)
#define MB1 17         // m-slots in merged gemm1 grid (worst case nL+nV)
#define MB2 17         // m-slots in merged gemm2 grid
#define KS2 5504       // gemm2 split-K half (= FF/2, 43*128)

using bf16x8  = __attribute__((ext_vector_type(8))) __bf16;
using f32x4   = __attribute__((ext_vector_type(4))) float;
using ushort8 = __attribute__((ext_vector_type(8))) unsigned short;

__device__ __forceinline__ int imin(int a, int b) { return a < b ? a : b; }

__device__ __forceinline__ unsigned short f2bf(float f) {
  union { float f; unsigned u; } v; v.f = f;
  unsigned r = v.u + 0x7fffu + ((v.u >> 16) & 1u);
  return (unsigned short)(r >> 16);
}

__device__ __forceinline__ void gld_lds16(const void* g, void* l) {
  __builtin_amdgcn_global_load_lds(
      (__attribute__((address_space(1))) void*)g,
      (__attribute__((address_space(3))) void*)l, 16, 0, 0);
}

// ---- detect int32 vs int64 storage of token_type_ids ----
__global__ void detect_mode(const int* __restrict__ w, int* __restrict__ flag) {
  int acc = 0;
  for (int i = 1 + 2 * (int)threadIdx.x; i < BL; i += 512) acc |= w[i];
  if (acc != 0) atomicOr(flag, 1);
}

// ---- vision mask + index compaction ----
__global__ void mask_compact(const int* __restrict__ w, const int* __restrict__ flag,
                             int* __restrict__ cnts, int* __restrict__ idxL,
                             int* __restrict__ idxV) {
  int i = blockIdx.x * 256 + threadIdx.x;
  if (i >= BL) return;
  int p = i & (LL - 1);
  bool i32 = (*flag != 0);
  int ti = i32 ? w[i] : w[2 * i];
  bool vis = false;
  if (p < LL - 1) {
    int tn = i32 ? w[i + 1] : w[2 * (i + 1)];
    vis = (ti == 1) && (tn == 1);
  }
  if (vis) idxV[atomicAdd(&cnts[1], 1)] = i;
  else     idxL[atomicAdd(&cnts[0], 1)] = i;
}

// ---- hidden_states fp32 -> bf16 ----
__global__ void convx(const float* __restrict__ x, unsigned short* __restrict__ xb) {
  size_t i = ((size_t)blockIdx.x * 256 + threadIdx.x) * 8;
  float4 a = *(const float4*)(x + i);
  float4 b = *(const float4*)(x + i + 4);
  ushort8 o;
  o[0] = f2bf(a.x); o[1] = f2bf(a.y); o[2] = f2bf(a.z); o[3] = f2bf(a.w);
  o[4] = f2bf(b.x); o[5] = f2bf(b.y); o[6] = f2bf(b.z); o[7] = f2bf(b.w);
  *(ushort8*)(xb + i) = o;
}

// ---- weight transpose + convert (round-8 proven): [K][N] fp32 -> [rmap(N)][K] bf16
__global__ void convT(const float* __restrict__ in, unsigned short* __restrict__ out,
                      int K, int N, int toff) {
  __shared__ unsigned short T[64][65];
  int n0 = blockIdx.x * 64, k0 = blockIdx.y * 64;
  int t = threadIdx.x;
  int cg = (t & 15) * 4;
  int r0 = t >> 4;
#pragma unroll
  for (int it = 0; it < 4; ++it) {
    int r = r0 + it * 16;
    float4 v = *(const float4*)(in + (size_t)(k0 + r) * N + n0 + cg);
    T[cg + 0][r] = f2bf(v.x); T[cg + 1][r] = f2bf(v.y);
    T[cg + 2][r] = f2bf(v.z); T[cg + 3][r] = f2bf(v.w);
  }
  __syncthreads();
  int nl = t >> 3, kg = t & 7;
#pragma unroll
  for (int it = 0; it < 2; ++it) {
    int n = nl + it * 32;
    ushort8 o;
#pragma unroll
    for (int j = 0; j < 8; ++j) o[j] = T[n][kg * 8 + j];
    int gn = n0 + n;
    size_t r = (toff < 0) ? (size_t)gn
                          : (size_t)(((gn >> 4) << 5) + toff + (gn & 15));
    *(ushort8*)(out + r * K + k0 + kg * 8) = o;
  }
}

// ---- split-K reduction: out = P0 + P1 (dense, every token written) ----
__global__ void reduce2(const float* __restrict__ P, float* __restrict__ out) {
  size_t i = ((size_t)blockIdx.x * 256 + threadIdx.x) * 4;
  float4 a = *(const float4*)(P + i);
  float4 b = *(const float4*)(P + (size_t)BL * HD + i);
  float4 o = make_float4(a.x + b.x, a.y + b.y, a.z + b.z, a.w + b.w);
  *(float4*)(out + i) = o;
}

// ===========================================================================
// Shared 256x256-tile 8-phase pipeline macros (validated round-3/5 ledger):
//   P1 A(kt1)h0   P2 A(kt1)h1   P3 B(kt2)h0   P4 B(kt2)h1 +vmcnt(4)
//   P5 A(kt2)h0   P6 A(kt2)h1   P7 B(kt3)h0   P8 B(kt3)h1 +vmcnt(4)
// ===========================================================================
#define BAR()  __builtin_amdgcn_s_barrier()
#define VMC(n) asm volatile("s_waitcnt vmcnt(" #n ")" ::: "memory")
#define LGK0() asm volatile("s_waitcnt lgkmcnt(0)" ::: "memory")

#define STG_A(h, kt) { \
  gld_lds16(aptr[h][0] + (size_t)(kt) * 64, &lds[(((kt) & 1) << 14) + ((h) << 13) + w * 512]); \
  gld_lds16(aptr[h][1] + (size_t)(kt) * 64, &lds[(((kt) & 1) << 14) + ((h) << 13) + (w + 8) * 512]); }
#define STG_B(h, kt) { \
  gld_lds16(bptr[h][0] + (size_t)(kt) * 64, &lds[32768 + (((kt) & 1) << 14) + ((h) << 13) + w * 512]); \
  gld_lds16(bptr[h][1] + (size_t)(kt) * 64, &lds[32768 + (((kt) & 1) << 14) + ((h) << 13) + (w + 8) * 512]); }

#define RD_A(s, rh) { _Pragma("unroll") \
  for (int mi = 0; mi < 4; ++mi) { \
    a[mi][0] = *(const bf16x8*)&lds[((s) << 14) + addrA[rh][mi]]; \
    a[mi][1] = *(const bf16x8*)&lds[((s) << 14) + (addrA[rh][mi] ^ 32)]; } }
#define RD_B(s, ch, br) { _Pragma("unroll") \
  for (int ni = 0; ni < 2; ++ni) { \
    br[ni][0] = *(const bf16x8*)&lds[((s) << 14) + addrB[ch][ni]]; \
    br[ni][1] = *(const bf16x8*)&lds[((s) << 14) + (addrB[ch][ni] ^ 32)]; } }

#define MFMA_Q(rh, br, ch) { \
  __builtin_amdgcn_s_setprio(1); \
  _Pragma("unroll") for (int mi = 0; mi < 4; ++mi) \
  _Pragma("unroll") for (int ni = 0; ni < 2; ++ni) { \
    acc[(rh)*4+mi][(ch)*2+ni] = __builtin_amdgcn_mfma_f32_16x16x32_bf16(a[mi][0], br[ni][0], acc[(rh)*4+mi][(ch)*2+ni], 0, 0, 0); \
    acc[(rh)*4+mi][(ch)*2+ni] = __builtin_amdgcn_mfma_f32_16x16x32_bf16(a[mi][1], br[ni][1], acc[(rh)*4+mi][(ch)*2+ni], 0, 0, 0); } \
  __builtin_amdgcn_s_setprio(0); }

// Body: K-loop over KEXT (multiple of 128, KEXT/64-1 odd), using aptr/bptr/addrA/addrB/acc.
#define KLOOP_8PH(KEXT) \
  STG_A(0, 0); STG_A(1, 0); STG_B(0, 0); STG_B(1, 0); \
  STG_B(0, 1); STG_B(1, 1); \
  VMC(4); BAR(); \
  for (int i = 0; i < (KEXT) / 128 - 1; ++i) { \
    const int kt1 = 2 * i + 1, kt2 = 2 * i + 2, kt3 = 2 * i + 3; \
    RD_A(0, 0); RD_B(0, 0, b0); STG_A(0, kt1); BAR(); LGK0(); \
    MFMA_Q(0, b0, 0); BAR(); \
    RD_B(0, 1, b1); STG_A(1, kt1); BAR(); LGK0(); \
    MFMA_Q(0, b1, 1); BAR(); \
    RD_A(0, 1); STG_B(0, kt2); BAR(); LGK0(); \
    MFMA_Q(1, b0, 0); BAR(); \
    STG_B(1, kt2); VMC(4); BAR(); \
    MFMA_Q(1, b1, 1); BAR(); \
    RD_A(1, 0); RD_B(1, 0, b0); STG_A(0, kt2); BAR(); LGK0(); \
    MFMA_Q(0, b0, 0); BAR(); \
    RD_B(1, 1, b1); STG_A(1, kt2); BAR(); LGK0(); \
    MFMA_Q(0, b1, 1); BAR(); \
    RD_A(1, 1); STG_B(0, kt3); BAR(); LGK0(); \
    MFMA_Q(1, b0, 0); BAR(); \
    STG_B(1, kt3); VMC(4); BAR(); \
    MFMA_Q(1, b1, 1); BAR(); \
  } \
  { \
    const int kt1 = (KEXT) / 64 - 1; \
    RD_A(0, 0); RD_B(0, 0, b0); STG_A(0, kt1); BAR(); LGK0(); \
    MFMA_Q(0, b0, 0); BAR(); \
    RD_B(0, 1, b1); STG_A(1, kt1); BAR(); LGK0(); \
    MFMA_Q(0, b1, 1); BAR(); \
    RD_A(0, 1); BAR(); LGK0(); \
    MFMA_Q(1, b0, 0); BAR(); \
    VMC(0); BAR(); \
    MFMA_Q(1, b1, 1); BAR(); \
    RD_A(1, 0); RD_B(1, 0, b0); BAR(); LGK0(); \
    MFMA_Q(0, b0, 0); BAR(); \
    RD_B(1, 1, b1); BAR(); LGK0(); \
    MFMA_Q(0, b1, 1); BAR(); \
    RD_A(1, 1); BAR(); LGK0(); \
    MFMA_Q(1, b0, 0); BAR(); \
    BAR(); \
    MFMA_Q(1, b1, 1); BAR(); \
  }

// ===========================================================================
// GEMM1 merged: both experts, one dispatch. Padded bijective XCD map:
// grid 1464 = 8*183; wgid = xcd*183+pos; bx = wgid/17, mb = wgid%17.
// ===========================================================================
__global__ __launch_bounds__(512, 2) void gemm1m_8ph(
    const unsigned short* __restrict__ Xb,
    const unsigned short* __restrict__ Wgu0, const unsigned short* __restrict__ Wgu1,
    const int* __restrict__ idxL, const int* __restrict__ idxV,
    const int* __restrict__ cnts, unsigned short* __restrict__ H) {
  const int orig = blockIdx.x;
  const int xcd = orig & 7;
  const int pos = orig >> 3;
  const int wgid = xcd * 183 + pos;
  const int bx = wgid / MB1;
  int mb = wgid - bx * MB1;
  if (bx >= NN) return;
  const int cntL = cnts[0], cntV = cnts[1];
  const int nL = (cntL + 255) >> 8;
  const int* idx; const unsigned short* Wgu; int cnt;
  if (mb < nL) { idx = idxL; Wgu = Wgu0; cnt = cntL; }
  else {
    mb -= nL;
    if (mb >= ((cntV + 255) >> 8)) return;
    idx = idxV; Wgu = Wgu1; cnt = cntV;
  }
  const int m0 = mb << 8;

  __shared__ __align__(16) unsigned short lds[65536];

  const int t = threadIdx.x, l = t & 63, w = t >> 6;
  const int wr = w >> 2, wc = w & 3;
  const int srcswz = (((l & 7) ^ (l >> 3)) << 3);

  const unsigned short* aptr[2][2];
  const unsigned short* bptr[2][2];
#pragma unroll
  for (int h = 0; h < 2; ++h)
#pragma unroll
    for (int j = 0; j < 2; ++j) {
      int r = h * 128 + (w + j * 8) * 8 + (l >> 3);
      int tok = idx[imin(m0 + r, cnt - 1)];
      aptr[h][j] = Xb + (size_t)tok * HD + srcswz;
      bptr[h][j] = Wgu + (size_t)(bx * 256 + r) * HD + srcswz;
    }

  const int koff0 = (((l >> 4) ^ (l & 7)) << 3);
  int addrA[2][4], addrB[2][2];
#pragma unroll
  for (int rh = 0; rh < 2; ++rh)
#pragma unroll
    for (int mi = 0; mi < 4; ++mi)
      addrA[rh][mi] = (wr * 128 + rh * 64 + mi * 16 + (l & 15)) * 64 + koff0;
#pragma unroll
  for (int ch = 0; ch < 2; ++ch)
#pragma unroll
    for (int ni = 0; ni < 2; ++ni)
      addrB[ch][ni] = 32768 + (wc * 64 + ch * 32 + ni * 16 + (l & 15)) * 64 + koff0;

  f32x4 acc[8][4] = {};
  bf16x8 a[4][2], b0[2][2], b1[2][2];

  KLOOP_8PH(HD)

#pragma unroll
  for (int mi = 0; mi < 8; ++mi)
#pragma unroll
    for (int j = 0; j < 4; ++j) {
      int grow = m0 + wr * 128 + mi * 16 + ((l >> 4) << 2) + j;
      if (grow < cnt) {
        int token = idx[grow];
#pragma unroll
        for (int pair = 0; pair < 2; ++pair) {
          float g = acc[mi][pair * 2][j];
          float u = acc[mi][pair * 2 + 1][j];
          float h = (g / (1.f + __expf(-g))) * u;
          int f = bx * 128 + wc * 32 + pair * 16 + (l & 15);
          H[(size_t)token * FF + f] = f2bf(h);
        }
      }
    }
}

// ===========================================================================
// GEMM2 merged + split-K=2: partial[s] = h[:, s*5504:(s+1)*5504] @ Wd-half.
// Grid 544 = 8*68; wgid = xcd*68+pos; s = wgid/272; bx = (wgid%272)/17,
// mb = wgid%17 (fastest -> 17 consumers of (s,bx) co-resident per XCD).
// Writes fp32 partials P[s][token][HD]; reduce2 sums them into out.
// ===========================================================================
__global__ __launch_bounds__(512, 2) void gemm2_8ph(
    const unsigned short* __restrict__ Hh,
    const unsigned short* __restrict__ Wd0, const unsigned short* __restrict__ Wd1,
    const int* __restrict__ idxL, const int* __restrict__ idxV,
    const int* __restrict__ cnts, float* __restrict__ P) {
  const int orig = blockIdx.x;
  const int xcd = orig & 7;
  const int pos = orig >> 3;
  const int wgid = xcd * 68 + pos;            // 544 = 8*68
  const int sK = wgid / (16 * MB2);           // 0 or 1
  const int rr = wgid - sK * (16 * MB2);
  const int bx = rr / MB2;
  int mb = rr - bx * MB2;
  const int cntL = cnts[0], cntV = cnts[1];
  const int nL = (cntL + 255) >> 8;
  const int* idx; const unsigned short* Wd; int cnt;
  if (mb < nL) { idx = idxL; Wd = Wd0; cnt = cntL; }
  else {
    mb -= nL;
    if (mb >= ((cntV + 255) >> 8)) return;
    idx = idxV; Wd = Wd1; cnt = cntV;
  }
  const int m0 = mb << 8;
  const size_t kbase = (size_t)sK * KS2;

  __shared__ __align__(16) unsigned short lds[65536];

  const int t = threadIdx.x, l = t & 63, w = t >> 6;
  const int wr = w >> 2, wc = w & 3;
  const int srcswz = (((l & 7) ^ (l >> 3)) << 3);

  const unsigned short* aptr[2][2];
  const unsigned short* bptr[2][2];
#pragma unroll
  for (int h = 0; h < 2; ++h)
#pragma unroll
    for (int j = 0; j < 2; ++j) {
      int r = h * 128 + (w + j * 8) * 8 + (l >> 3);
      int tok = idx[imin(m0 + r, cnt - 1)];
      aptr[h][j] = Hh + (size_t)tok * FF + kbase + srcswz;
      bptr[h][j] = Wd + (size_t)(bx * 256 + r) * FF + kbase + srcswz;
    }

  const int koff0 = (((l >> 4) ^ (l & 7)) << 3);
  int addrA[2][4], addrB[2][2];
#pragma unroll
  for (int rh = 0; rh < 2; ++rh)
#pragma unroll
    for (int mi = 0; mi < 4; ++mi)
      addrA[rh][mi] = (wr * 128 + rh * 64 + mi * 16 + (l & 15)) * 64 + koff0;
#pragma unroll
  for (int ch = 0; ch < 2; ++ch)
#pragma unroll
    for (int ni = 0; ni < 2; ++ni)
      addrB[ch][ni] = 32768 + (wc * 64 + ch * 32 + ni * 16 + (l & 15)) * 64 + koff0;

  f32x4 acc[8][4] = {};
  bf16x8 a[4][2], b0[2][2], b1[2][2];

  KLOOP_8PH(KS2)

  float* Pout = P + (size_t)sK * BL * HD;
#pragma unroll
  for (int mi = 0; mi < 8; ++mi)
#pragma unroll
    for (int j = 0; j < 4; ++j) {
      int grow = m0 + wr * 128 + mi * 16 + ((l >> 4) << 2) + j;
      if (grow < cnt) {
        int token = idx[grow];
        size_t base = (size_t)token * HD + bx * 256 + wc * 64 + (l & 15);
#pragma unroll
        for (int nf = 0; nf < 4; ++nf)
          Pout[base + nf * 16] = acc[mi][nf][j];
      }
    }
}

extern "C" void kernel_launch(void* const* d_in, const int* in_sizes, int n_in,
                              void* d_out, int out_size, void* d_ws, size_t ws_size,
                              hipStream_t stream) {
  const float* hs = (const float*)d_in[0];
  const int*   tt = (const int*)d_in[1];
  const float* lg = (const float*)d_in[2];
  const float* lu = (const float*)d_in[3];
  const float* ld = (const float*)d_in[4];
  const float* vg = (const float*)d_in[5];
  const float* vu = (const float*)d_in[6];
  const float* vd = (const float*)d_in[7];
  float* out = (float*)d_out;
  char* ws = (char*)d_ws;

  int* cnts = (int*)ws;
  int* flag = (int*)(ws + 8);
  int* idxL = (int*)(ws + 1024);
  int* idxV = (int*)(ws + 1024 + BL * 4);
  unsigned short* Xb   = (unsigned short*)(ws + 65536);
  unsigned short* Hb   = Xb + (size_t)BL * HD;
  unsigned short* Wgu0 = Hb + (size_t)BL * FF;          // 180.4 MB
  unsigned short* Wgu1 = Wgu0 + (size_t)2 * HD * FF;    // 180.4 MB
  unsigned short* Wd0  = Wgu0;                          // reused after gemm1
  unsigned short* Wd1  = Wgu0 + (size_t)HD * FF;
  float* Pk = (float*)(Wgu0 + (size_t)2 * HD * FF);     // 134.2 MB in free tail

  hipMemsetAsync(ws, 0, 64, stream);
  detect_mode<<<1, 256, 0, stream>>>(tt, flag);
  mask_compact<<<BL / 256, 256, 0, stream>>>(tt, flag, cnts, idxL, idxV);
  convx<<<(BL * HD / 8) / 256, 256, 0, stream>>>(hs, Xb);

  // both experts' gate/up interleaved -> one merged gemm1 dispatch
  convT<<<dim3(FF / 64, HD / 64), 256, 0, stream>>>(lg, Wgu0, HD, FF, 0);
  convT<<<dim3(FF / 64, HD / 64), 256, 0, stream>>>(lu, Wgu0, HD, FF, 16);
  convT<<<dim3(FF / 64, HD / 64), 256, 0, stream>>>(vg, Wgu1, HD, FF, 0);
  convT<<<dim3(FF / 64, HD / 64), 256, 0, stream>>>(vu, Wgu1, HD, FF, 16);
  gemm1m_8ph<<<dim3(8 * 183), 512, 0, stream>>>(Xb, Wgu0, Wgu1, idxL, idxV, cnts, Hb);

  // down projections: split-K=2 partials + reduction
  convT<<<dim3(HD / 64, FF / 64), 256, 0, stream>>>(ld, Wd0, FF, HD, -1);
  convT<<<dim3(HD / 64, FF / 64), 256, 0, stream>>>(vd, Wd1, FF, HD, -1);
  gemm2_8ph<<<dim3(8 * 68), 512, 0, stream>>>(Hb, Wd0, Wd1, idxL, idxV, cnts, Pk);
  reduce2<<<dim3((size_t)BL * HD / 4 / 256), 256, 0, stream>>>(Pk, out);
}